// Round 5
// baseline (224.412 us; speedup 1.0000x reference)
//
#include <hip/hip_runtime.h>
#include <hip/hip_bf16.h>

// Fused adapter: out = relu(LN(x) @ Wd + bd) @ Wu + bu
// LN folded into GEMM1:  down = rs*(x @ (gamma⊙Wd)) - rs*mu*s + t
// R5: R3/R4 math; x staged via global_load_lds DMA (no VGPR dest => compiler
// cannot sink it; queue depth 8KB/wave). R4 showed hipcc collapses register
// double-buffers (VGPR=64), pinning per-wave MLP at ~2 loads => 1.9 TB/s.
//  - chunk = 4 kk (16 rows x 128 cols f32 = 8KB = 8 DMA instrs), dbuf in LDS
//  - one conservative vmcnt(0)+sched_barrier per chunk (robust vs compiler
//    interleaving its weight loads into the vmcnt queue; still ~43KB/CU in
//    flight by Little's law vs 9.2KB needed for 6.3 TB/s)
//  - LDS layout [kk][cg][row] granules: DMA's linear lane order baked in via
//    per-lane global addresses (wave-uniform LDS base); ds_read_b128 pairs
//    give uniform 8 accesses/bank = conflict-free-optimal

#define D_MODEL 768
#define KB      64
#define NTHR    256     // 4 waves, each an independent 16-row tile
#define PPAD    72      // 64 + 8 bf16 pad

#define CH2     6       // N-tiles per GEMM2 chunk (48 total -> 8 chunks)
#define NCH2    8

typedef __attribute__((ext_vector_type(8))) short    bf16x8;
typedef __attribute__((ext_vector_type(4))) float    f32x4;
typedef __attribute__((ext_vector_type(4))) unsigned short us4;

static __device__ __forceinline__ unsigned short f2bf(float f) {
  // RNE f32 -> bf16 (inputs finite)
  unsigned int u = __builtin_bit_cast(unsigned int, f);
  unsigned int r = u + 0x7FFFu + ((u >> 16) & 1u);
  return (unsigned short)(r >> 16);
}

static __device__ __forceinline__ void gload16(const void* g, void* l) {
  // 16B per lane: global (per-lane addr) -> LDS (wave-uniform base + lane*16)
  __builtin_amdgcn_global_load_lds(
      (const __attribute__((address_space(1))) unsigned int*)g,
      (__attribute__((address_space(3))) unsigned int*)l, 16, 0, 0);
}

// ---------------- prep kernel: 49 blocks x 1024 thr ----------------
__global__ void __launch_bounds__(1024) adapter_prep(
    const float* __restrict__ wd,
    const float* __restrict__ wu,
    const float* __restrict__ gamma,
    const float* __restrict__ beta,
    const float* __restrict__ bdown,
    unsigned short* __restrict__ wdT,
    unsigned short* __restrict__ wuT,
    float* __restrict__ s_arr,
    float* __restrict__ t_arr) {
  const int b = blockIdx.x;
  const int t = threadIdx.x;
  if (b < 48) {
    const int i = b * 1024 + t;         // 0..49151
    const int k1 = i / D_MODEL;
    const int d1 = i - k1 * D_MODEL;
    wdT[i] = f2bf(gamma[d1] * wd[(size_t)d1 * KB + k1]);
    const int d2 = i >> 6;
    const int k2 = i & 63;
    wuT[i] = f2bf(wu[(size_t)k2 * D_MODEL + d2]);
  } else {
    const int k = t & 63;
    const int c = t >> 6;               // 0..15, 48 d's each
    float ss = 0.f, tt = 0.f;
    const int d0 = c * 48;
    #pragma unroll 4
    for (int d = d0; d < d0 + 48; ++d) {
      const float w = wd[(size_t)d * KB + k];
      ss = fmaf(gamma[d], w, ss);
      tt = fmaf(beta[d],  w, tt);
    }
    __shared__ float ps[16][64], pt[16][64];
    ps[c][k] = ss; pt[c][k] = tt;
    __syncthreads();
    if (t < 64) {
      float S = 0.f, T = 0.f;
      #pragma unroll
      for (int q = 0; q < 16; ++q) { S += ps[q][t]; T += pt[q][t]; }
      s_arr[t] = S;
      t_arr[t] = T + bdown[t];
    }
  }
}

// ---------------- main fused kernel ----------------
__global__ void __launch_bounds__(NTHR, 2) adapter_main(
    const float* __restrict__ x,
    const float* __restrict__ s_arr,
    const float* __restrict__ t_arr,
    const unsigned short* __restrict__ wdT,
    const unsigned short* __restrict__ wuT,
    const float* __restrict__ b_up,
    float* __restrict__ out) {

  // per-wave double-buffered x stage: [wave][buf][8KB]
  // granule G (16B) in a buffer: G = kk*128 + cg*16 + r  (kk 0..3, cg 0..7, r 0..15)
  // DMA instr n writes granules 64n+l: kk=n>>1, cg=4*(n&1)+(l>>4), r=l&15
  __shared__ __align__(16) unsigned char xs[4][2][8192];   // 64 KiB
  __shared__ unsigned short p_s[4][16][PPAD];              //  9 KiB

  const int t   = threadIdx.x;
  const int wid = t >> 6;
  const int l   = t & 63;
  const int lr  = l & 15;      // fragment lane index
  const int lg  = l >> 4;      // k-group
  const int row0 = blockIdx.x * 64 + wid * 16;  // this wave's 16 rows

  // per-lane global source base for DMA: row (l&15), col-granule part (l>>4)
  const float* xlane = x + (size_t)(row0 + lr) * D_MODEL + lg * 4;
  unsigned char* xb[2] = { &xs[wid][0][0], &xs[wid][1][0] };

  // weight base (A-frag): wdT[16c+lr][32kk+8lg+e]
  const unsigned short* wp = wdT + (size_t)lr * D_MODEL + 8 * lg;

  f32x4 acc[4];
  #pragma unroll
  for (int c = 0; c < 4; ++c) acc[c] = (f32x4){0.f, 0.f, 0.f, 0.f};
  float s1 = 0.f, s2 = 0.f;

  // ---- prologue: DMA chunk 0 ----
  #pragma unroll
  for (int n = 0; n < 8; ++n)
    gload16(xlane + 32 * (n >> 1) + 16 * (n & 1), xb[0] + 1024 * n);

  // ---- GEMM1: 6 chunks x 4 kk ----
  #pragma unroll
  for (int ch = 0; ch < 6; ++ch) {
    const int cur = ch & 1;
    // weight frags for this chunk (16x 16B, L2-resident; drained by the wait)
    bf16x8 wf[4][4];
    #pragma unroll
    for (int c = 0; c < 4; ++c)
      #pragma unroll
      for (int j = 0; j < 4; ++j)
        wf[j][c] = *(const bf16x8*)(wp + (size_t)16 * c * D_MODEL + 32 * (4 * ch + j));
    // issue next chunk's DMA before waiting (stays in flight across the wait? no:
    // vmcnt(0) drains it too — but it was issued 8-deep, so the drain IS the
    // HBM-BW-limited arrival of 8KB, overlapped across the 8 waves/CU)
    if (ch < 5) {
      const float* g = xlane + 128 * (ch + 1);
      #pragma unroll
      for (int n = 0; n < 8; ++n)
        gload16(g + 32 * (n >> 1) + 16 * (n & 1), xb[cur ^ 1] + 1024 * n);
    }
    asm volatile("s_waitcnt vmcnt(0)" ::: "memory");
    __builtin_amdgcn_sched_barrier(0);
    // consume chunk ch from LDS
    #pragma unroll
    for (int j = 0; j < 4; ++j) {
      const unsigned char* cb = xb[cur] + 2048 * j + 512 * lg + 16 * lr;
      const f32x4 va = *(const f32x4*)(cb);          // cols 8lg+0..3
      const f32x4 vb = *(const f32x4*)(cb + 256);    // cols 8lg+4..7
      s1 += (va[0] + va[1]) + (va[2] + va[3]) + (vb[0] + vb[1]) + (vb[2] + vb[3]);
      s2 = fmaf(va[0], va[0], s2); s2 = fmaf(va[1], va[1], s2);
      s2 = fmaf(va[2], va[2], s2); s2 = fmaf(va[3], va[3], s2);
      s2 = fmaf(vb[0], vb[0], s2); s2 = fmaf(vb[1], vb[1], s2);
      s2 = fmaf(vb[2], vb[2], s2); s2 = fmaf(vb[3], vb[3], s2);
      bf16x8 xf;
      xf[0] = (short)f2bf(va[0]); xf[1] = (short)f2bf(va[1]);
      xf[2] = (short)f2bf(va[2]); xf[3] = (short)f2bf(va[3]);
      xf[4] = (short)f2bf(vb[0]); xf[5] = (short)f2bf(vb[1]);
      xf[6] = (short)f2bf(vb[2]); xf[7] = (short)f2bf(vb[3]);
      #pragma unroll
      for (int c = 0; c < 4; ++c)
        acc[c] = __builtin_amdgcn_mfma_f32_16x16x32_bf16(wf[j][c], xf, acc[c], 0, 0, 0);
    }
  }

  // ---- LN stats: row lr's sums live in lanes {lr, lr+16, lr+32, lr+48} ----
  s1 += __shfl_xor(s1, 16); s1 += __shfl_xor(s1, 32);
  s2 += __shfl_xor(s2, 16); s2 += __shfl_xor(s2, 32);
  const float mu  = s1 * (1.0f / 768.0f);
  const float var = s2 * (1.0f / 768.0f) - mu * mu;
  const float rs  = rsqrtf(var + 1e-5f);
  const float nm  = -rs * mu;

  // ---- epilogue: LN correction + ReLU + bf16 -> wave-private LDS patch ----
  // lane reg j is down[row lr][col 16c+4lg+j]
  #pragma unroll
  for (int c = 0; c < 4; ++c) {
    const float4 sv = *(const float4*)(s_arr + 16 * c + 4 * lg);
    const float4 tv = *(const float4*)(t_arr + 16 * c + 4 * lg);
    us4 pk;
    pk.x = f2bf(fmaxf(fmaf(rs, acc[c][0], fmaf(nm, sv.x, tv.x)), 0.f));
    pk.y = f2bf(fmaxf(fmaf(rs, acc[c][1], fmaf(nm, sv.y, tv.y)), 0.f));
    pk.z = f2bf(fmaxf(fmaf(rs, acc[c][2], fmaf(nm, sv.z, tv.z)), 0.f));
    pk.w = f2bf(fmaxf(fmaf(rs, acc[c][3], fmaf(nm, sv.w, tv.w)), 0.f));
    *(us4*)&p_s[wid][lr][16 * c + 4 * lg] = pk;
  }
  // no barrier: patch is wave-private; compiler inserts the lgkmcnt wait

  // ---- GEMM2: out rows = P(16x64) @ Wu, 48 N-tiles, double-buffered ----
  const bf16x8 pa0 = *(const bf16x8*)&p_s[wid][lr][8 * lg];        // k 0..31
  const bf16x8 pa1 = *(const bf16x8*)&p_s[wid][lr][32 + 8 * lg];   // k 32..63
  float* op = out + (size_t)(row0 + 4 * lg) * D_MODEL + lr;

  bf16x8 wb[2][CH2][2];
  float  bb[2][CH2];
  #pragma unroll
  for (int j = 0; j < CH2; ++j) {
    const int cn = 16 * j;
    const unsigned short* bp = wuT + (size_t)(cn + lr) * KB + 8 * lg;
    wb[0][j][0] = *(const bf16x8*)(bp);
    wb[0][j][1] = *(const bf16x8*)(bp + 32);
    bb[0][j]    = b_up[cn + lr];
  }
  #pragma unroll
  for (int ch = 0; ch < NCH2; ++ch) {
    const int cur = ch & 1, nxt = cur ^ 1;
    if (ch < NCH2 - 1) {
      #pragma unroll
      for (int j = 0; j < CH2; ++j) {
        const int cn = 16 * (CH2 * (ch + 1) + j);
        const unsigned short* bp = wuT + (size_t)(cn + lr) * KB + 8 * lg;
        wb[nxt][j][0] = *(const bf16x8*)(bp);
        wb[nxt][j][1] = *(const bf16x8*)(bp + 32);
        bb[nxt][j]    = b_up[cn + lr];
      }
    }
    #pragma unroll
    for (int j = 0; j < CH2; ++j) {
      const int cn = 16 * (CH2 * ch + j);
      f32x4 c0 = {0.f, 0.f, 0.f, 0.f};
      c0 = __builtin_amdgcn_mfma_f32_16x16x32_bf16(pa0, wb[cur][j][0], c0, 0, 0, 0);
      c0 = __builtin_amdgcn_mfma_f32_16x16x32_bf16(pa1, wb[cur][j][1], c0, 0, 0, 0);
      const float bu = bb[cur][j];
      op[(size_t)0 * D_MODEL + cn] = c0[0] + bu;
      op[(size_t)1 * D_MODEL + cn] = c0[1] + bu;
      op[(size_t)2 * D_MODEL + cn] = c0[2] + bu;
      op[(size_t)3 * D_MODEL + cn] = c0[3] + bu;
    }
  }
}

// ---------------- launch ----------------
extern "C" void kernel_launch(void* const* d_in, const int* in_sizes, int n_in,
                              void* d_out, int out_size, void* d_ws, size_t ws_size,
                              hipStream_t stream) {
  const float* x     = (const float*)d_in[0];
  const float* gamma = (const float*)d_in[1];
  const float* beta  = (const float*)d_in[2];
  const float* wd    = (const float*)d_in[3];
  const float* bdown = (const float*)d_in[4];
  const float* wu    = (const float*)d_in[5];
  const float* bup   = (const float*)d_in[6];
  float* out = (float*)d_out;

  char* ws = (char*)d_ws;
  unsigned short* wdT = (unsigned short*)ws;                    // 96 KiB
  unsigned short* wuT = (unsigned short*)(ws + 98304);          // 96 KiB
  float* s_arr = (float*)(ws + 196608);                         // 256 B
  float* t_arr = (float*)(ws + 196864);                         // 256 B

  const int rows = in_sizes[0] / D_MODEL;       // 32768

  adapter_prep<<<49, 1024, 0, stream>>>(wd, wu, gamma, beta, bdown,
                                        wdT, wuT, s_arr, t_arr);
  adapter_main<<<rows / 64, NTHR, 0, stream>>>(x, s_arr, t_arr, wdT, wuT, bup, out);
}

// Round 7
// 203.269 us; speedup vs baseline: 1.1040x; 1.1040x over previous
//
#include <hip/hip_runtime.h>
#include <hip/hip_bf16.h>

// Fused adapter: out = relu(LN(x) @ Wd + bd) @ Wu + bu
// LN folded into GEMM1:  down = rs*(x @ (gamma⊙Wd)) - rs*mu*s + t
// R6 (resubmitted R7 after acquisition timeout): full-wave-contiguous I/O.
// R1-R5 all pinned at ~2 TB/s with 64-256B-segment scattered access
// (16 segs/instr reads, 4 segs/instr writes) across 3 different structures
// => granularity/segment-count theory.
//  - reads: x staged via global_load_lds size-4 (256B contiguous per instr),
//    K chunked 6x128, dbuf, vmcnt(0)+barrier per chunk, next DMA after barrier
//  - writes: C staged in LDS (overlay x bufs), cooperative 1KB-contiguous
//    float4 stores (m13 pattern), 3 column-chunks of 256
//  - stats from the f32 fragment reads (no separate pass); cvt_pk bf16 pack

#define D_MODEL 768
#define KB      64
#define BMR     32      // rows per block
#define NTHR    256     // 4 waves
#define XSTR    132     // x-stage row stride in floats (128 + 4 pad)
#define OSTR    260     // out-stage row stride in floats (256 + 4 pad)
#define PPAD    72      // p_s row stride in shorts (64 + 8 pad)

typedef __attribute__((ext_vector_type(8))) short    bf16x8;
typedef __attribute__((ext_vector_type(4))) float    f32x4;

static __device__ __forceinline__ unsigned short f2bf(float f) {
  unsigned int u = __builtin_bit_cast(unsigned int, f);
  unsigned int r = u + 0x7FFFu + ((u >> 16) & 1u);
  return (unsigned short)(r >> 16);
}

static __device__ __forceinline__ bf16x8 pack_bf8(const f32x4 a, const f32x4 b) {
  // 4x v_cvt_pk_bf16_f32 via HIP intrinsic (RNE)
  union { __hip_bfloat162 h2[4]; bf16x8 v; } u;
  u.h2[0] = __float22bfloat162_rn({a[0], a[1]});
  u.h2[1] = __float22bfloat162_rn({a[2], a[3]});
  u.h2[2] = __float22bfloat162_rn({b[0], b[1]});
  u.h2[3] = __float22bfloat162_rn({b[2], b[3]});
  return u.v;
}

static __device__ __forceinline__ void gload4(const float* g, float* lds) {
  // 4B/lane: global per-lane addr -> LDS wave-uniform base + lane*4
  __builtin_amdgcn_global_load_lds(
      (const __attribute__((address_space(1))) unsigned int*)g,
      (__attribute__((address_space(3))) unsigned int*)lds, 4, 0, 0);
}

// ---------------- prep kernel: 49 blocks x 1024 thr ----------------
__global__ void __launch_bounds__(1024) adapter_prep(
    const float* __restrict__ wd,
    const float* __restrict__ wu,
    const float* __restrict__ gamma,
    const float* __restrict__ beta,
    const float* __restrict__ bdown,
    unsigned short* __restrict__ wdT,
    unsigned short* __restrict__ wuT,
    float* __restrict__ s_arr,
    float* __restrict__ t_arr) {
  const int b = blockIdx.x;
  const int t = threadIdx.x;
  if (b < 48) {
    const int i = b * 1024 + t;         // 0..49151
    const int k1 = i / D_MODEL;
    const int d1 = i - k1 * D_MODEL;
    wdT[i] = f2bf(gamma[d1] * wd[(size_t)d1 * KB + k1]);
    const int d2 = i >> 6;
    const int k2 = i & 63;
    wuT[i] = f2bf(wu[(size_t)k2 * D_MODEL + d2]);
  } else {
    const int k = t & 63;
    const int c = t >> 6;               // 0..15, 48 d's each
    float ss = 0.f, tt = 0.f;
    const int d0 = c * 48;
    #pragma unroll 4
    for (int d = d0; d < d0 + 48; ++d) {
      const float w = wd[(size_t)d * KB + k];
      ss = fmaf(gamma[d], w, ss);
      tt = fmaf(beta[d],  w, tt);
    }
    __shared__ float ps[16][64], pt[16][64];
    ps[c][k] = ss; pt[c][k] = tt;
    __syncthreads();
    if (t < 64) {
      float S = 0.f, T = 0.f;
      #pragma unroll
      for (int q = 0; q < 16; ++q) { S += ps[q][t]; T += pt[q][t]; }
      s_arr[t] = S;
      t_arr[t] = T + bdown[t];
    }
  }
}

// ---------------- main fused kernel ----------------
__global__ void __launch_bounds__(NTHR, 4) adapter_main(
    const float* __restrict__ x,
    const float* __restrict__ s_arr,
    const float* __restrict__ t_arr,
    const unsigned short* __restrict__ wdT,
    const unsigned short* __restrict__ wuT,
    const float* __restrict__ b_up,
    float* __restrict__ out) {

  // x stage: 2 bufs x [32 rows][132 floats] = 33792 B; out-stage overlays it
  // ([32][260] f32 = 33280 B). p_s separate: [32][72] u16 = 4608 B.
  __shared__ __align__(16) unsigned char lds_raw[2 * BMR * XSTR * 4];
  __shared__ unsigned short p_s[BMR][PPAD];

  float* xs0 = (float*)lds_raw;
  float* xs1 = (float*)(lds_raw + BMR * XSTR * 4);
  float* os  = (float*)lds_raw;

  const int t   = threadIdx.x;
  const int wid = t >> 6;
  const int l   = t & 63;
  const int lr  = l & 15;
  const int lg  = l >> 4;
  const int row0 = blockIdx.x * BMR;

  // ---- DMA staging: wave wid stages rows 8wid..8wid+7; instr = 256B of a row
  auto stage = [&](int ck, float* buf) {
    #pragma unroll
    for (int i = 0; i < 8; ++i) {
      const int r = 8 * wid + i;
      const float* g0 = x + (size_t)(row0 + r) * D_MODEL + ck * 128 + l;
      gload4(g0,      buf + r * XSTR);
      gload4(g0 + 64, buf + r * XSTR + 64);
    }
  };

  // GEMM1: wave wid owns down-cols 16wid..16wid+15 (B = gamma⊙Wd via wdT)
  const unsigned short* wrow = wdT + (size_t)(16 * wid + lr) * D_MODEL + 8 * lg;

  f32x4 acc0 = {0.f, 0.f, 0.f, 0.f};   // rows 0..15
  f32x4 acc1 = {0.f, 0.f, 0.f, 0.f};   // rows 16..31
  float s1a = 0.f, s2a = 0.f, s1b = 0.f, s2b = 0.f;

  stage(0, xs0);          // prologue

  #pragma unroll
  for (int ch = 0; ch < 6; ++ch) {
    float* cb = (ch & 1) ? xs1 : xs0;
    float* nb = (ch & 1) ? xs0 : xs1;
    asm volatile("s_waitcnt vmcnt(0)" ::: "memory");   // my DMAs for ch done
    __builtin_amdgcn_sched_barrier(0);
    __syncthreads();                                    // everyone's ch done
    if (ch < 5) stage(ch + 1, nb);                      // overlaps consume
    #pragma unroll
    for (int kkL = 0; kkL < 4; ++kkL) {
      const int kk = 4 * ch + kkL;
      const bf16x8 wq = *(const bf16x8*)(wrow + 32 * kk);
      const float* pa_ = cb + lr * XSTR + kkL * 32 + 8 * lg;
      const float* pb_ = cb + (16 + lr) * XSTR + kkL * 32 + 8 * lg;
      const f32x4 a0 = *(const f32x4*)(pa_);
      const f32x4 a1 = *(const f32x4*)(pa_ + 4);
      const f32x4 b0 = *(const f32x4*)(pb_);
      const f32x4 b1 = *(const f32x4*)(pb_ + 4);
      s1a += (a0[0] + a0[1]) + (a0[2] + a0[3]) + (a1[0] + a1[1]) + (a1[2] + a1[3]);
      s2a = fmaf(a0[0], a0[0], s2a); s2a = fmaf(a0[1], a0[1], s2a);
      s2a = fmaf(a0[2], a0[2], s2a); s2a = fmaf(a0[3], a0[3], s2a);
      s2a = fmaf(a1[0], a1[0], s2a); s2a = fmaf(a1[1], a1[1], s2a);
      s2a = fmaf(a1[2], a1[2], s2a); s2a = fmaf(a1[3], a1[3], s2a);
      s1b += (b0[0] + b0[1]) + (b0[2] + b0[3]) + (b1[0] + b1[1]) + (b1[2] + b1[3]);
      s2b = fmaf(b0[0], b0[0], s2b); s2b = fmaf(b0[1], b0[1], s2b);
      s2b = fmaf(b0[2], b0[2], s2b); s2b = fmaf(b0[3], b0[3], s2b);
      s2b = fmaf(b1[0], b1[0], s2b); s2b = fmaf(b1[1], b1[1], s2b);
      s2b = fmaf(b1[2], b1[2], s2b); s2b = fmaf(b1[3], b1[3], s2b);
      const bf16x8 xa = pack_bf8(a0, a1);
      const bf16x8 xb = pack_bf8(b0, b1);
      acc0 = __builtin_amdgcn_mfma_f32_16x16x32_bf16(xa, wq, acc0, 0, 0, 0);
      acc1 = __builtin_amdgcn_mfma_f32_16x16x32_bf16(xb, wq, acc1, 0, 0, 0);
    }
  }

  // ---- stats: reduce over lg (lanes lr, lr+16, lr+32, lr+48) ----
  s1a += __shfl_xor(s1a, 16); s1a += __shfl_xor(s1a, 32);
  s2a += __shfl_xor(s2a, 16); s2a += __shfl_xor(s2a, 32);
  s1b += __shfl_xor(s1b, 16); s1b += __shfl_xor(s1b, 32);
  s2b += __shfl_xor(s2b, 16); s2b += __shfl_xor(s2b, 32);

  // ---- epilogue: LN correction + ReLU -> p_s[row][16wid+lr] ----
  const int pcol = 16 * wid + lr;
  const float sk = s_arr[pcol];
  const float tk = t_arr[pcol];
  #pragma unroll
  for (int j = 0; j < 4; ++j) {
    // row 4lg+j (group a) and 16+4lg+j (group b); stats live at lane 4lg+j
    const float ma1 = __shfl(s1a, 4 * lg + j), ma2 = __shfl(s2a, 4 * lg + j);
    const float mb1 = __shfl(s1b, 4 * lg + j), mb2 = __shfl(s2b, 4 * lg + j);
    const float mua = ma1 * (1.0f / 768.0f);
    const float rsa = rsqrtf(ma2 * (1.0f / 768.0f) - mua * mua + 1e-5f);
    const float mub = mb1 * (1.0f / 768.0f);
    const float rsb = rsqrtf(mb2 * (1.0f / 768.0f) - mub * mub + 1e-5f);
    const float da = fmaxf(fmaf(rsa, acc0[j], fmaf(-rsa * mua, sk, tk)), 0.f);
    const float db = fmaxf(fmaf(rsb, acc1[j], fmaf(-rsb * mub, sk, tk)), 0.f);
    p_s[4 * lg + j][pcol]      = f2bf(da);
    p_s[16 + 4 * lg + j][pcol] = f2bf(db);
  }

  __syncthreads();   // p_s visible to all; xs consumed -> os overlay safe

  // ---- GEMM2: P(32x64) @ Wu; wave wid owns cols 64wid.. within each 256-chunk
  bf16x8 pA[2][2];
  pA[0][0] = *(const bf16x8*)&p_s[lr][8 * lg];
  pA[0][1] = *(const bf16x8*)&p_s[lr][32 + 8 * lg];
  pA[1][0] = *(const bf16x8*)&p_s[16 + lr][8 * lg];
  pA[1][1] = *(const bf16x8*)&p_s[16 + lr][32 + 8 * lg];

  #pragma unroll
  for (int g = 0; g < 3; ++g) {
    if (g) __syncthreads();           // prev chunk's store-reads done
    #pragma unroll
    for (int q = 0; q < 4; ++q) {
      const int col = 256 * g + 64 * wid + 16 * q + lr;   // global out col
      const unsigned short* bp = wuT + (size_t)col * KB + 8 * lg;
      const bf16x8 wb0 = *(const bf16x8*)(bp);
      const bf16x8 wb1 = *(const bf16x8*)(bp + 32);
      f32x4 c0 = {0.f, 0.f, 0.f, 0.f};
      f32x4 c1 = {0.f, 0.f, 0.f, 0.f};
      c0 = __builtin_amdgcn_mfma_f32_16x16x32_bf16(pA[0][0], wb0, c0, 0, 0, 0);
      c0 = __builtin_amdgcn_mfma_f32_16x16x32_bf16(pA[0][1], wb1, c0, 0, 0, 0);
      c1 = __builtin_amdgcn_mfma_f32_16x16x32_bf16(pA[1][0], wb0, c1, 0, 0, 0);
      c1 = __builtin_amdgcn_mfma_f32_16x16x32_bf16(pA[1][1], wb1, c1, 0, 0, 0);
      const float bu = b_up[col];
      const int cl = 64 * wid + 16 * q + lr;              // col within os
      #pragma unroll
      for (int j = 0; j < 4; ++j) {
        os[(4 * lg + j) * OSTR + cl]        = c0[j] + bu;
        os[(16 + 4 * lg + j) * OSTR + cl]   = c1[j] + bu;
      }
    }
    __syncthreads();                  // os complete
    // cooperative contiguous stores: 1KB per instr (64 lanes x float4)
    #pragma unroll
    for (int i = 0; i < 8; ++i) {
      const int r = 8 * wid + i;
      const f32x4 v = *(const f32x4*)&os[r * OSTR + 4 * l];
      *(f32x4*)(out + (size_t)(row0 + r) * D_MODEL + 256 * g + 4 * l) = v;
    }
  }
}

// ---------------- launch ----------------
extern "C" void kernel_launch(void* const* d_in, const int* in_sizes, int n_in,
                              void* d_out, int out_size, void* d_ws, size_t ws_size,
                              hipStream_t stream) {
  const float* x     = (const float*)d_in[0];
  const float* gamma = (const float*)d_in[1];
  const float* beta  = (const float*)d_in[2];
  const float* wd    = (const float*)d_in[3];
  const float* bdown = (const float*)d_in[4];
  const float* wu    = (const float*)d_in[5];
  const float* bup   = (const float*)d_in[6];
  float* out = (float*)d_out;

  char* ws = (char*)d_ws;
  unsigned short* wdT = (unsigned short*)ws;                    // 96 KiB
  unsigned short* wuT = (unsigned short*)(ws + 98304);          // 96 KiB
  float* s_arr = (float*)(ws + 196608);                         // 256 B
  float* t_arr = (float*)(ws + 196864);                         // 256 B

  const int rows = in_sizes[0] / D_MODEL;       // 32768

  adapter_prep<<<49, 1024, 0, stream>>>(wd, wu, gamma, beta, bdown,
                                        wdT, wuT, s_arr, t_arr);
  adapter_main<<<rows / BMR, NTHR, 0, stream>>>(x, s_arr, t_arr, wdT, wuT, bup, out);
}